// Round 1
// baseline (148.027 us; speedup 1.0000x reference)
//
#include <hip/hip_runtime.h>

// Problem constants (fixed by reference)
#define D_DIRS 1024
#define P_PTS  256
#define R_RANK 64
#define K_SUB  1024

typedef float v4f __attribute__((ext_vector_type(4)));

// Workspace layout in floats:
//   a[D][R]      @ 0        (65536)
//   b[D][R]      @ 65536    (65536)
//   Msum[64][64] @ 131072   (4096)   -- zeroed by k1 block 0, atomically
//                                       accumulated by k_partial_m.
#define WS_A 0
#define WS_B (D_DIRS * R_RANK)
#define WS_MSUM (2 * D_DIRS * R_RANK)
#define NB_B 32
#define DCHUNK (D_DIRS / NB_B) // 32

__device__ __forceinline__ v4f ntload(const v4f* __restrict__ p) {
    return __builtin_nontemporal_load(p);
}

__device__ __forceinline__ v4f shfl_xor_v4(v4f v, int m) {
    v4f r;
    r.x = __shfl_xor(v.x, m);
    r.y = __shfl_xor(v.y, m);
    r.z = __shfl_xor(v.z, m);
    r.w = __shfl_xor(v.w, m);
    return r;
}

// ---------------------------------------------------------------------------
// Kernel 1: p-reduction.  a[d,r] = sum_p atten[d,p,r]; b likewise.
// R7 restructure for occupancy: 1024 blocks x 256 threads (was 256x512).
//   - one d per block; wave w owns p-quarter [w*64, w*64+64), FULL r-width.
//   - lane = pr(2b)|r4g(4b): each wave-load instruction covers 4 complete
//     p-rows = 64 contiguous float4 = 1 KiB fully-coalesced (vs 8x128B
//     segments before).
//   - pipeline: 4-load chunks, 2-deep => 16 v4f buffers (~half the VGPR of
//     R5's 32), __launch_bounds__(256,4) => 4 waves/SIMD => 16 waves/CU,
//     2x the outstanding loads of R5's 8 waves/CU, 4 blocks/CU for tail
//     smoothing.
//   - r-reduction: shfl_xor 16/32 within wave (pr axis), then one LDS
//     combine across the 4 waves at the very end (off the streaming path).
// Block 0 additionally zero-inits Msum (harness poisons ws with 0xAA;
// kernel boundary orders the zeroing before k_partial_m's atomics).
// ---------------------------------------------------------------------------
__global__ __launch_bounds__(256, 4) void k_reduce_p(const float* __restrict__ atten,
                                                     const float* __restrict__ rad,
                                                     float* __restrict__ ws) {
    const int t    = threadIdx.x;
    const int wave = t >> 6;     // 0..3 -> p-quarter
    const int lane = t & 63;
    const int pr   = lane >> 4;  // 0..3  p-row within 4-row group
    const int r4g  = lane & 15;  // 0..15 float4 column (full r-width)
    const int d    = blockIdx.x;

    if (blockIdx.x == 0) { // zero Msum: 256 threads x 4 float4 = 4096 floats
        v4f z = {0.f, 0.f, 0.f, 0.f};
#pragma unroll
        for (int i = 0; i < 4; ++i)
            ((v4f*)(ws + WS_MSUM))[t + i * 256] = z;
    }

    // float4 index within the d-slab (4096 float4s): p*16 + r4g,
    // p = wave*64 + m*4 + pr, m = 0..15  =>  base + m*64.
    const int base = wave * 1024 + pr * 16 + r4g;
    const v4f* A4 = (const v4f*)atten + (size_t)d * 4096 + base;
    const v4f* B4 = (const v4f*)rad   + (size_t)d * 4096 + base;

    v4f pa[4], pb[4], na[4], nb[4];
#pragma unroll
    for (int j = 0; j < 4; ++j) pa[j] = ntload(A4 + j * 64);
#pragma unroll
    for (int j = 0; j < 4; ++j) pb[j] = ntload(B4 + j * 64);

    v4f acc_a = {0.f, 0.f, 0.f, 0.f};
    v4f acc_b = {0.f, 0.f, 0.f, 0.f};

#pragma unroll
    for (int c = 0; c < 4; ++c) {
        if (c < 3) {
            const int off = (c + 1) * 256; // 4 loads * 64 float4 stride
#pragma unroll
            for (int j = 0; j < 4; ++j) na[j] = ntload(A4 + off + j * 64);
#pragma unroll
            for (int j = 0; j < 4; ++j) nb[j] = ntload(B4 + off + j * 64);
        }
        acc_a = acc_a + ((pa[0] + pa[1]) + (pa[2] + pa[3]));
        acc_b = acc_b + ((pb[0] + pb[1]) + (pb[2] + pb[3]));
#pragma unroll
        for (int j = 0; j < 4; ++j) { pa[j] = na[j]; pb[j] = nb[j]; }
    }

    // Reduce across pr (lanes sharing r4g): xor 16, 32.
    acc_a = acc_a + shfl_xor_v4(acc_a, 16);
    acc_a = acc_a + shfl_xor_v4(acc_a, 32);
    acc_b = acc_b + shfl_xor_v4(acc_b, 16);
    acc_b = acc_b + shfl_xor_v4(acc_b, 32);

    // Cross-wave combine (4 quarters) via LDS, single barrier at kernel end.
    __shared__ v4f sA[4][16];
    __shared__ v4f sB[4][16];
    if (lane < 16) {
        sA[wave][r4g] = acc_a;
        sB[wave][r4g] = acc_b;
    }
    __syncthreads();
    if (t < 16) {
        v4f a = (sA[0][t] + sA[1][t]) + (sA[2][t] + sA[3][t]);
        v4f b = (sB[0][t] + sB[1][t]) + (sB[2][t] + sB[3][t]);
        ((v4f*)(ws + WS_A))[d * 16 + t] = a;
        ((v4f*)(ws + WS_B))[d * 16 + t] = b;
    }
}

// ---------------------------------------------------------------------------
// Kernel 2: M accumulation.  Block bb covers d in [bb*32, bb*32+32); computes
// its 64x64 partial in registers then atomicAdds into Msum (32-way contention
// per address — 131K atomics total, negligible; fp32 reassociation is well
// inside the absmax threshold: we sit at 1.0 vs 37.8).
// ---------------------------------------------------------------------------
__global__ __launch_bounds__(256) void k_partial_m(float* __restrict__ ws) {
    const int bb = blockIdx.x;
    const int t  = threadIdx.x;

    __shared__ float sa[DCHUNK * R_RANK]; // 8 KiB
    __shared__ float sb[DCHUNK * R_RANK]; // 8 KiB

    const float4* a4 = (const float4*)(ws + WS_A) + bb * (DCHUNK * R_RANK / 4);
    const float4* b4 = (const float4*)(ws + WS_B) + bb * (DCHUNK * R_RANK / 4);
    float4* sa4 = (float4*)sa;
    float4* sb4 = (float4*)sb;
    sa4[t]       = a4[t];
    sa4[t + 256] = a4[t + 256];
    sb4[t]       = b4[t];
    sb4[t + 256] = b4[t + 256];
    __syncthreads();

    const int c  = t & 63;
    const int wg = t >> 6;

    float acc[16];
#pragma unroll
    for (int i = 0; i < 16; ++i) acc[i] = 0.f;

    for (int dd = 0; dd < DCHUNK; ++dd) {
        const float bv = sb[dd * 64 + c];
        const float4* ar = (const float4*)&sa[dd * 64 + wg * 16];
        const float4 a0 = ar[0], a1 = ar[1], a2 = ar[2], a3 = ar[3];
        acc[0]  += a0.x * bv; acc[1]  += a0.y * bv; acc[2]  += a0.z * bv; acc[3]  += a0.w * bv;
        acc[4]  += a1.x * bv; acc[5]  += a1.y * bv; acc[6]  += a1.z * bv; acc[7]  += a1.w * bv;
        acc[8]  += a2.x * bv; acc[9]  += a2.y * bv; acc[10] += a2.z * bv; acc[11] += a2.w * bv;
        acc[12] += a3.x * bv; acc[13] += a3.y * bv; acc[14] += a3.z * bv; acc[15] += a3.w * bv;
    }

    float* Msum = ws + WS_MSUM;
#pragma unroll
    for (int i = 0; i < 16; ++i)
        atomicAdd(&Msum[(wg * 16 + i) * 64 + c], acc[i]);
}

// ---------------------------------------------------------------------------
// Kernel 3: csi[k] = (1/D) F[k] Msum F[k]^T.
// 16 blocks x 256 threads; block bb owns k in [bb*64, bb*64+64).
// Fs padded stride 65 -> conflict-free; Ms reads are wave-uniform broadcasts.
// ---------------------------------------------------------------------------
__global__ __launch_bounds__(256) void k_csi(const float* __restrict__ ws,
                                             const float* __restrict__ freq,
                                             float* __restrict__ out) {
    const int bb = blockIdx.x;
    const int t  = threadIdx.x;

    __shared__ float Ms[64 * 68];   // ~17 KiB
    __shared__ float Fs[64 * 65];   // ~16.6 KiB
    __shared__ float red[4][64];

    const float4* M4 = (const float4*)(ws + WS_MSUM);
#pragma unroll
    for (int i = 0; i < 4; ++i) {
        const int idx4 = i * 256 + t;
        const float4 s = M4[idx4];
        const int r = idx4 >> 4, c4 = idx4 & 15;
        *(float4*)&Ms[r * 68 + c4 * 4] = s;
    }

    const float4* F4 = (const float4*)freq + bb * 1024;
#pragma unroll
    for (int i = 0; i < 4; ++i) {
        const int idx4 = i * 256 + t;
        const float4 v = F4[idx4];
        const int row = idx4 >> 4, c4 = idx4 & 15;
        Fs[row * 65 + c4 * 4 + 0] = v.x;
        Fs[row * 65 + c4 * 4 + 1] = v.y;
        Fs[row * 65 + c4 * 4 + 2] = v.z;
        Fs[row * 65 + c4 * 4 + 3] = v.w;
    }
    __syncthreads();

    const int kl = t & 63;
    const int jg = t >> 6;

    float h[16];
#pragma unroll
    for (int j = 0; j < 16; ++j) h[j] = 0.f;

    for (int r = 0; r < 64; ++r) {
        const float fv = Fs[kl * 65 + r];
        const float4* mr = (const float4*)&Ms[r * 68 + jg * 16];
        const float4 m0 = mr[0], m1 = mr[1], m2 = mr[2], m3 = mr[3];
        h[0]  += fv * m0.x; h[1]  += fv * m0.y; h[2]  += fv * m0.z; h[3]  += fv * m0.w;
        h[4]  += fv * m1.x; h[5]  += fv * m1.y; h[6]  += fv * m1.z; h[7]  += fv * m1.w;
        h[8]  += fv * m2.x; h[9]  += fv * m2.y; h[10] += fv * m2.z; h[11] += fv * m2.w;
        h[12] += fv * m3.x; h[13] += fv * m3.y; h[14] += fv * m3.z; h[15] += fv * m3.w;
    }

    float part = 0.f;
#pragma unroll
    for (int j = 0; j < 16; ++j) part += h[j] * Fs[kl * 65 + jg * 16 + j];

    red[jg][kl] = part;
    __syncthreads();
    if (t < 64) {
        out[bb * 64 + t] =
            (red[0][t] + red[1][t] + red[2][t] + red[3][t]) * (1.0f / (float)D_DIRS);
    }
}

extern "C" void kernel_launch(void* const* d_in, const int* in_sizes, int n_in,
                              void* d_out, int out_size, void* d_ws, size_t ws_size,
                              hipStream_t stream) {
    const float* atten = (const float*)d_in[0]; // (D,P,R)
    const float* rad   = (const float*)d_in[1]; // (D,P,R)
    const float* freq  = (const float*)d_in[2]; // (K,R)
    float* out = (float*)d_out;                 // (K,)
    float* ws  = (float*)d_ws;                  // needs 528 KiB

    k_reduce_p<<<D_DIRS, 256, 0, stream>>>(atten, rad, ws);
    k_partial_m<<<NB_B, 256, 0, stream>>>(ws);
    k_csi<<<16, 256, 0, stream>>>(ws, freq, out);
}